// Round 6
// baseline (2546.835 us; speedup 1.0000x reference)
//
#include <hip/hip_runtime.h>

// DSTP-RNN fused implementation for MI355X (gfx950).
// Structural facts (proved from the reference):
//  * encoder softmaxes over D are invariant to the recurrent-state terms -> a1,a2 precomputable
//  * LSTM1 is dead (its state only feeds a cancelled softmax shift)
//  * decoder ctx is only used via ctx.fc_w and ctx.ff_w[256:] -> per-(b,t) scalars cf/cff
//  * all recurrences are independent per batch row -> per-tile kernels, no grid sync
// Dtype handling: harness hands fp32 (reference dtype) or bf16; k_detect sniffs and
// all raw-input reads use a branchless u16 load at (i<<sh)+ad.
// R6 change: k_dec __launch_bounds__(512,1). R5's (512,2) under CUDA blocks/CU
// semantics = 16 waves/CU = 4 waves/EU = exactly the 128-VGPR budget we were
// already at -> xq/sc spilled to scratch (FETCH stayed 2.2 GB, VGPR stayed 128).
// (512,1) gives >=256 VGPRs under either semantics; grid=256 is 1 block/CU anyway.

typedef unsigned short u16;
using bf16x8 = __attribute__((ext_vector_type(8))) short;   // 8 bf16 = 4 VGPRs (MFMA A/B frag)
using f32x4  = __attribute__((ext_vector_type(4))) float;   // MFMA C/D frag

__device__ __forceinline__ float bf2f(u16 u){
  union { unsigned int i; float f; } v; v.i = ((unsigned int)u) << 16; return v.f;
}
__device__ __forceinline__ u16 f2bf(float f){
  union { float f; unsigned int i; } v; v.f = f;
  unsigned int x = v.i;
  return (u16)((x + 0x7fffu + ((x >> 16) & 1u)) >> 16);  // RNE
}
// raw bf16 bits of input element i under dtype mode (sh,ad)
__device__ __forceinline__ u16 ldraw(const void* p, size_t i, int sh, int ad){
  return *(const u16*)((const char*)p + (i << sh) + ad);
}
__device__ __forceinline__ float ldf(const void* p, size_t i, int sh, int ad){
  return bf2f(ldraw(p, i, sh, ad));
}
__device__ __forceinline__ float sigm(float x){ return __builtin_amdgcn_rcpf(1.f + __expf(-x)); }
__device__ __forceinline__ float ftanh(float x){
  float e = __expf(2.f * x);
  return 1.f - 2.f * __builtin_amdgcn_rcpf(e + 1.f);
}

// ---------------------------------------------------------------------------
// k_detect: decide input dtype. flag=1 -> bf16, flag=0 -> fp32.
// ---------------------------------------------------------------------------
__global__ void k_detect(const u16* __restrict__ Xu, int* __restrict__ flag){
  if (threadIdx.x == 0 && blockIdx.x == 0){
    int bad = 0;
    for (int i = 0; i < 128; ++i){
      u16 u = Xu[2 * i];
      int ex = (u >> 7) & 0xFF;
      if (!(u == 0 || u == 0x8000 || (ex >= 64 && ex <= 191))) bad = 1;
    }
    *flag = bad ? 0 : 1;
  }
}

// ---------------------------------------------------------------------------
// k_attn: wmul[b][d] = a1[b][d]*a2[b][d], d in [0,96) (81 valid, pad 0), fp32.
// ---------------------------------------------------------------------------
__global__ __launch_bounds__(256) void k_attn(const void* __restrict__ X,
    const void* __restrict__ e1w, const void* __restrict__ e2w,
    float* __restrict__ wmul, const int* __restrict__ flagp){
  int F = *flagp, sh = 2 - F, ad = F ? 0 : 2;
  int wv = threadIdx.x >> 6, lane = threadIdx.x & 63;
  int b = blockIdx.x * 4 + wv;
  size_t xb0 = (size_t)b * (15 * 81);
  float s1a = 0.f, s1b = 0.f, s2a = 0.f, s2b = 0.f;
  int d1 = 64 + lane;
  bool v1 = d1 < 81;
  #pragma unroll
  for (int t = 0; t < 15; ++t){
    float w1 = ldf(e1w, 512 + t, sh, ad), w2 = ldf(e2w, 512 + t, sh, ad); // w1x,w2x at [2*He:]
    float xa = ldf(X, xb0 + t * 81 + lane, sh, ad);
    float xb = v1 ? ldf(X, xb0 + t * 81 + d1, sh, ad) : 0.f;
    s1a += w1 * xa; s1b += w1 * xb;
    s2a += w2 * xa; s2b += w2 * xb;
  }
  if (!v1){ s1b = -1e30f; s2b = -1e30f; }
  float m1 = fmaxf(s1a, s1b), m2 = fmaxf(s2a, s2b);
  for (int o = 32; o; o >>= 1){ m1 = fmaxf(m1, __shfl_xor(m1, o)); m2 = fmaxf(m2, __shfl_xor(m2, o)); }
  float e1a = __expf(s1a - m1), e1b = v1 ? __expf(s1b - m1) : 0.f;
  float e2a = __expf(s2a - m2), e2b = v1 ? __expf(s2b - m2) : 0.f;
  float S1 = e1a + e1b, S2 = e2a + e2b;
  for (int o = 32; o; o >>= 1){ S1 += __shfl_xor(S1, o); S2 += __shfl_xor(S2, o); }
  float inv = 1.f / (S1 * S2);
  wmul[(size_t)b * 96 + lane] = e1a * e2a * inv;
  if (lane < 32) wmul[(size_t)b * 96 + d1] = v1 ? e1b * e2b * inv : 0.f;
}

// ---------------------------------------------------------------------------
// k_pack: repack weights into MFMA B-fragment order. Frag (nt,kc): element
// ((nt*KC+kc)*64+lane)*8+j holds W[n=nt*16+(lane&15)][k=kc*32+(lane>>4)*8+j].
// ---------------------------------------------------------------------------
__global__ __launch_bounds__(256) void k_pack(const void* __restrict__ l2_wih,
    const void* __restrict__ l2_whh, const void* __restrict__ dl_whh,
    const void* __restrict__ da1w, u16* __restrict__ Wenc, u16* __restrict__ Wd6,
    u16* __restrict__ Wd1, u16* __restrict__ Wxp, const int* __restrict__ flagp){
  int F = *flagp, sh = 2 - F, ad = F ? 0 : 2;
  int e = blockIdx.x * 256 + threadIdx.x;
  if (e >= 819200) return;
  if (e < 360448){
    int j = e & 7, lane = (e >> 3) & 63, fc = e >> 9;
    int nt = fc / 11, kc = fc - nt * 11;
    int n = nt * 16 + (lane & 15), k = kc * 32 + (lane >> 4) * 8 + j;
    u16 v = 0;
    if (k < 81) v = ldraw(l2_wih, n * 81 + k, sh, ad);
    else if (k >= 96) v = ldraw(l2_whh, n * 256 + (k - 96), sh, ad);
    Wenc[e] = v;
  } else if (e < 360448 + 262144){
    int e2 = e - 360448;
    int j = e2 & 7, lane = (e2 >> 3) & 63, fc = e2 >> 9;
    int kc = fc & 7, nt = fc >> 3;
    int n = nt * 16 + (lane & 15), k = kc * 32 + (lane >> 4) * 8 + j;
    Wd6[e2] = ldraw(dl_whh, n * 256 + k, sh, ad);
  } else if (e < 360448 + 262144 + 131072){
    int e3 = e - (360448 + 262144);
    int j = e3 & 7, lane = (e3 >> 3) & 63, fc = e3 >> 9;
    int kc = fc & 15, nt = fc >> 4;
    int n = nt * 16 + (lane & 15), k = kc * 32 + (lane >> 4) * 8 + j;
    Wd1[e3] = ldraw(da1w, n * 768 + k, sh, ad);
  } else {
    int e4 = e - (360448 + 262144 + 131072);
    int j = e4 & 7, lane = (e4 >> 3) & 63, fc = e4 >> 9;
    int kc = fc & 7, nt = fc >> 3;
    int n = nt * 16 + (lane & 15), k = kc * 32 + (lane >> 4) * 8 + j;
    Wxp[e4] = ldraw(da1w, n * 768 + 512 + k, sh, ad);
  }
}

// ---------------------------------------------------------------------------
// k_enc: LSTM2 over 15 steps, 32 rows/block (grid 256), 8 waves. Per step the
// LSTM pointwise is followed by xp_t = h_t @ W1x^T + d_a1_b (global write) plus
// scalars cf=h.fc_w, cff=h.ffw[256:].
// ---------------------------------------------------------------------------
__global__ __launch_bounds__(512) void k_enc(const void* __restrict__ X,
    const float* __restrict__ wmul, const u16* __restrict__ Wenc,
    const u16* __restrict__ Wxp, const void* __restrict__ l2_b,
    const void* __restrict__ da1b, const void* __restrict__ fcw,
    const void* __restrict__ ffw, u16* __restrict__ xp,
    float* __restrict__ cfg, float* __restrict__ cffg,
    const int* __restrict__ flagp){
  __shared__ u16 A_s[32 * 360];        // [m][k]: k<96 = x_tilde2 (pad0), k in [96,352) = h
  __shared__ float w_s[32 * 96];
  __shared__ float cf_s[32], cff_s[32];
  int F = *flagp, sh = 2 - F, ad = F ? 0 : 2;
  int tid = threadIdx.x, wv = tid >> 6, lane = tid & 63, q = lane >> 4, ln = lane & 15;
  int b0 = blockIdx.x * 32;
  for (int i = tid; i < 32 * 96; i += 512){
    int m = i / 96;
    w_s[i] = wmul[(size_t)(b0 + m) * 96 + (i - m * 96)];
  }
  for (int i = tid; i < 32 * 360; i += 512) A_s[i] = 0;
  int u0 = wv * 32 + ln;
  float bi[2], bff[2], bg[2], bo[2], fcr[2], ffr[2], dbr[2];
  #pragma unroll
  for (int ut = 0; ut < 2; ++ut){
    int u = u0 + ut * 16;
    bi[ut]  = ldf(l2_b, u, sh, ad);        bff[ut] = ldf(l2_b, 256 + u, sh, ad);
    bg[ut]  = ldf(l2_b, 512 + u, sh, ad);  bo[ut]  = ldf(l2_b, 768 + u, sh, ad);
    fcr[ut] = ldf(fcw, u, sh, ad);         ffr[ut] = ldf(ffw, 256 + u, sh, ad);
    dbr[ut] = ldf(da1b, u, sh, ad);
  }
  float cst[2][2][4];
  #pragma unroll
  for (int a = 0; a < 2; ++a)
    for (int c = 0; c < 2; ++c)
      for (int r = 0; r < 4; ++r) cst[a][c][r] = 0.f;
  __syncthreads();
  const bf16x8* Wv  = (const bf16x8*)Wenc;
  const bf16x8* Wxv = (const bf16x8*)Wxp;
  const f32x4 vzero = {0.f, 0.f, 0.f, 0.f};
  for (int t = 0; t < 15; ++t){
    // ---- stage x_tilde2 = (a1*a2) .* x_t into A[:, 0:96) ----
    for (int i = tid; i < 32 * 96; i += 512){
      int m = i / 96, dd = i - m * 96;
      float v = 0.f;
      if (dd < 81) v = ldf(X, (size_t)(b0 + m) * 1215 + t * 81 + dd, sh, ad) * w_s[i];
      A_s[m * 360 + dd] = f2bf(v);
    }
    __syncthreads();   // s1
    if (tid < 64){ if (tid < 32) cf_s[tid] = 0.f; else cff_s[tid - 32] = 0.f; }
    // ---- gates GEMM: K=352 ----
    f32x4 acc[2][4][2];
    #pragma unroll
    for (int mt = 0; mt < 2; ++mt)
      for (int g = 0; g < 4; ++g)
        for (int ut = 0; ut < 2; ++ut) acc[mt][g][ut] = vzero;
    for (int kc = 0; kc < 11; ++kc){
      bf16x8 a0 = *(const bf16x8*)&A_s[ln * 360 + kc * 32 + q * 8];
      bf16x8 a1 = *(const bf16x8*)&A_s[(16 + ln) * 360 + kc * 32 + q * 8];
      #pragma unroll
      for (int g = 0; g < 4; ++g){
        #pragma unroll
        for (int ut = 0; ut < 2; ++ut){
          int ntg = g * 16 + wv * 2 + ut;
          bf16x8 bb = Wv[(ntg * 11 + kc) * 64 + lane];
          acc[0][g][ut] = __builtin_amdgcn_mfma_f32_16x16x32_bf16(a0, bb, acc[0][g][ut], 0, 0, 0);
          acc[1][g][ut] = __builtin_amdgcn_mfma_f32_16x16x32_bf16(a1, bb, acc[1][g][ut], 0, 0, 0);
        }
      }
    }
    __syncthreads();   // s2
    // ---- LSTM pointwise; h -> A_s[.,96+u]; cf/cff partial reductions ----
    #pragma unroll
    for (int mt = 0; mt < 2; ++mt){
      #pragma unroll
      for (int r = 0; r < 4; ++r){
        int m = mt * 16 + q * 4 + r;
        float pf = 0.f, pff = 0.f;
        #pragma unroll
        for (int ut = 0; ut < 2; ++ut){
          int u = u0 + ut * 16;
          float iv = acc[mt][0][ut][r] + bi[ut];
          float fv = acc[mt][1][ut][r] + bff[ut];
          float gv = acc[mt][2][ut][r] + bg[ut];
          float ov = acc[mt][3][ut][r] + bo[ut];
          float c2 = sigm(fv) * cst[mt][ut][r] + sigm(iv) * ftanh(gv);
          float h2 = sigm(ov) * ftanh(c2);
          cst[mt][ut][r] = c2;
          A_s[m * 360 + 96 + u] = f2bf(h2);
          pf  += h2 * fcr[ut];
          pff += h2 * ffr[ut];
        }
        pf  += __shfl_xor(pf, 1);  pf  += __shfl_xor(pf, 2);
        pf  += __shfl_xor(pf, 4);  pf  += __shfl_xor(pf, 8);
        pff += __shfl_xor(pff, 1); pff += __shfl_xor(pff, 2);
        pff += __shfl_xor(pff, 4); pff += __shfl_xor(pff, 8);
        if (ln == 0){ atomicAdd(&cf_s[m], pf); atomicAdd(&cff_s[m], pff); }
      }
    }
    __syncthreads();   // s3
    // ---- xp GEMM: xp_t[m][j] = h_t[m][:] @ W1x^T + da1b, K=256 ----
    f32x4 xpa[2][2];
    #pragma unroll
    for (int mt = 0; mt < 2; ++mt)
      for (int ut = 0; ut < 2; ++ut) xpa[mt][ut] = vzero;
    for (int kc = 0; kc < 8; ++kc){
      bf16x8 a0 = *(const bf16x8*)&A_s[ln * 360 + 96 + kc * 32 + q * 8];
      bf16x8 a1 = *(const bf16x8*)&A_s[(16 + ln) * 360 + 96 + kc * 32 + q * 8];
      #pragma unroll
      for (int ut = 0; ut < 2; ++ut){
        bf16x8 bb = Wxv[((wv * 2 + ut) * 8 + kc) * 64 + lane];
        xpa[0][ut] = __builtin_amdgcn_mfma_f32_16x16x32_bf16(a0, bb, xpa[0][ut], 0, 0, 0);
        xpa[1][ut] = __builtin_amdgcn_mfma_f32_16x16x32_bf16(a1, bb, xpa[1][ut], 0, 0, 0);
      }
    }
    #pragma unroll
    for (int mt = 0; mt < 2; ++mt){
      #pragma unroll
      for (int ut = 0; ut < 2; ++ut){
        int j = u0 + ut * 16;
        #pragma unroll
        for (int r = 0; r < 4; ++r){
          int m = mt * 16 + q * 4 + r;
          xp[((size_t)(b0 + m) * 15 + t) * 256 + j] = f2bf(xpa[mt][ut][r] + dbr[ut]);
        }
      }
    }
    if (tid < 32){
      cfg [(size_t)(b0 + tid) * 15 + t] = cf_s[tid];
      cffg[(size_t)(b0 + tid) * 15 + t] = cff_s[tid];
    }
  }
}

// ---------------------------------------------------------------------------
// k_dec: decoder, 32 rows/block (grid 256), 15 steps, 1 block/CU.
// __launch_bounds__(512,1) -> >=256-VGPR budget under either HIP/CUDA
// semantics, so the 128-u32 xq xp-cache stays in registers (no scratch).
// GEMM-6 runs as two 2-gate passes to keep peak live regs ~240.
// ---------------------------------------------------------------------------
__global__ __launch_bounds__(512, 1) void k_dec(const u16* __restrict__ xpv,
    const float* __restrict__ cfg, const float* __restrict__ cffg,
    const void* __restrict__ y_prev,
    const u16* __restrict__ Wd1, const u16* __restrict__ Wd6,
    const void* __restrict__ da2w, const void* __restrict__ dl_wih,
    const void* __restrict__ dl_b, const void* __restrict__ fcw,
    const void* __restrict__ fcb, const void* __restrict__ ffw,
    const void* __restrict__ ffb, void* __restrict__ outp,
    const int* __restrict__ flagp){
  __shared__ u16 A_s[32 * 552];        // [m][k]: k<256 = d, k in [256,512) = c (bf16)
  __shared__ float score_s[480], beta_s[480], cf_s[480], cff_s[480];
  __shared__ float yt_s[32];
  int F = *flagp, sh = 2 - F, ad = F ? 0 : 2;
  int tid = threadIdx.x, wv = tid >> 6, lane = tid & 63, q = lane >> 4, ln = lane & 15;
  int b0 = blockIdx.x * 32;
  int u0 = wv * 32 + ln;
  float w2v[2], wih_r[4][2], br[4][2];
  #pragma unroll
  for (int ut = 0; ut < 2; ++ut){
    int u = u0 + ut * 16;
    w2v[ut] = ldf(da2w, u, sh, ad);
    #pragma unroll
    for (int g = 0; g < 4; ++g){
      wih_r[g][ut] = ldf(dl_wih, g * 256 + u, sh, ad);
      br[g][ut]   = ldf(dl_b, g * 256 + u, sh, ad);
    }
  }
  float fcw256 = ldf(fcw, 256, sh, ad), fcbv = ldf(fcb, 0, sh, ad);
  float cst[2][2][4];
  #pragma unroll
  for (int a = 0; a < 2; ++a)
    for (int c = 0; c < 2; ++c)
      for (int r = 0; r < 4; ++r) cst[a][c][r] = 0.f;
  for (int i = tid; i < 32 * 552; i += 512) A_s[i] = 0;
  if (tid < 480){
    int row = tid / 15, tt = tid - row * 15;
    score_s[tid] = 0.f;
    cf_s [tid] = cfg [(size_t)(b0 + row) * 15 + tt];
    cff_s[tid] = cffg[(size_t)(b0 + row) * 15 + tt];
  }
  // ---- one-time xp slice preload: xq[mt][r][ut][p] = (tt=2p, tt=2p+1) bf16 pair ----
  unsigned int xq[2][4][2][8];
  #pragma unroll
  for (int mt = 0; mt < 2; ++mt){
    #pragma unroll
    for (int r = 0; r < 4; ++r){
      int m = mt * 16 + q * 4 + r;
      const u16* xr = xpv + (size_t)(b0 + m) * 15 * 256;
      #pragma unroll
      for (int ut = 0; ut < 2; ++ut){
        int j = u0 + ut * 16;
        #pragma unroll
        for (int p = 0; p < 8; ++p){
          unsigned int lo = xr[(2 * p) * 256 + j];
          unsigned int hi = (p < 7) ? (unsigned int)xr[(2 * p + 1) * 256 + j] : 0u;
          xq[mt][r][ut][p] = lo | (hi << 16);
        }
      }
    }
  }
  __syncthreads();
  const bf16x8* W1v = (const bf16x8*)Wd1;
  const bf16x8* W6v = (const bf16x8*)Wd6;
  const f32x4 vzero = {0.f, 0.f, 0.f, 0.f};
  for (int t = 0; t < 15; ++t){
    // ---- GEMM-1: proj[m][j] over K=512 ([d|c]) ----
    f32x4 p1[2][2];
    #pragma unroll
    for (int mt = 0; mt < 2; ++mt)
      for (int ut = 0; ut < 2; ++ut) p1[mt][ut] = vzero;
    for (int kc = 0; kc < 16; ++kc){
      bf16x8 a0 = *(const bf16x8*)&A_s[ln * 552 + kc * 32 + q * 8];
      bf16x8 a1 = *(const bf16x8*)&A_s[(16 + ln) * 552 + kc * 32 + q * 8];
      #pragma unroll
      for (int ut = 0; ut < 2; ++ut){
        bf16x8 bb = W1v[((wv * 2 + ut) * 16 + kc) * 64 + lane];
        p1[0][ut] = __builtin_amdgcn_mfma_f32_16x16x32_bf16(a0, bb, p1[0][ut], 0, 0, 0);
        p1[1][ut] = __builtin_amdgcn_mfma_f32_16x16x32_bf16(a1, bb, p1[1][ut], 0, 0, 0);
      }
    }
    // ---- score[m][tt] = sum_j w2[j]*tanh(xp[m][tt][j] + proj[m][j]) — regs only ----
    #pragma unroll
    for (int mt = 0; mt < 2; ++mt){
      #pragma unroll
      for (int r = 0; r < 4; ++r){
        int m = mt * 16 + q * 4 + r;
        float sc[15];
        #pragma unroll
        for (int tt = 0; tt < 15; ++tt) sc[tt] = 0.f;
        #pragma unroll
        for (int ut = 0; ut < 2; ++ut){
          float p = p1[mt][ut][r];
          #pragma unroll
          for (int tt = 0; tt < 15; ++tt){
            unsigned int pk = xq[mt][r][ut][tt >> 1];
            u16 raw = (tt & 1) ? (u16)(pk >> 16) : (u16)(pk & 0xffffu);
            sc[tt] += w2v[ut] * ftanh(p + bf2f(raw));
          }
        }
        #pragma unroll
        for (int tt = 0; tt < 15; ++tt){
          float v = sc[tt];
          v += __shfl_xor(v, 1); v += __shfl_xor(v, 2);
          v += __shfl_xor(v, 4); v += __shfl_xor(v, 8);
          if (ln == 0) atomicAdd(&score_s[m * 15 + tt], v);
        }
      }
    }
    __syncthreads();   // B: score atomics complete
    // ---- softmax over t + y_tilde (uses cf); re-zero score_s for next step ----
    if (tid < 32){
      float s[15]; float mx = -1e30f;
      #pragma unroll
      for (int tt = 0; tt < 15; ++tt){ s[tt] = score_s[tid * 15 + tt]; mx = fmaxf(mx, s[tt]); }
      float sum = 0.f;
      #pragma unroll
      for (int tt = 0; tt < 15; ++tt){ s[tt] = __expf(s[tt] - mx); sum += s[tt]; }
      float inv = 1.f / sum;
      float yt = fcbv + ldf(y_prev, (size_t)(b0 + tid) * 15 + t, sh, ad) * fcw256;
      #pragma unroll
      for (int tt = 0; tt < 15; ++tt){
        float bv = s[tt] * inv;
        beta_s[tid * 15 + tt] = bv;
        score_s[tid * 15 + tt] = 0.f;
        yt += bv * cf_s[tid * 15 + tt];
      }
      yt_s[tid] = yt;
    }
    __syncthreads();   // C: beta/yt/zeroed-score visible
    // ---- GEMM-6 pass A: gates i,f (K=256) -> iact, fterm (into cst) ----
    float iact[2][2][4];
    {
      f32x4 pA[2][2][2];
      #pragma unroll
      for (int mt = 0; mt < 2; ++mt)
        for (int g = 0; g < 2; ++g)
          for (int ut = 0; ut < 2; ++ut) pA[mt][g][ut] = vzero;
      for (int kc = 0; kc < 8; ++kc){
        bf16x8 a0 = *(const bf16x8*)&A_s[ln * 552 + kc * 32 + q * 8];
        bf16x8 a1 = *(const bf16x8*)&A_s[(16 + ln) * 552 + kc * 32 + q * 8];
        #pragma unroll
        for (int g = 0; g < 2; ++g){
          #pragma unroll
          for (int ut = 0; ut < 2; ++ut){
            bf16x8 bb = W6v[((g * 16 + wv * 2 + ut) * 8 + kc) * 64 + lane];
            pA[0][g][ut] = __builtin_amdgcn_mfma_f32_16x16x32_bf16(a0, bb, pA[0][g][ut], 0, 0, 0);
            pA[1][g][ut] = __builtin_amdgcn_mfma_f32_16x16x32_bf16(a1, bb, pA[1][g][ut], 0, 0, 0);
          }
        }
      }
      #pragma unroll
      for (int mt = 0; mt < 2; ++mt){
        #pragma unroll
        for (int ut = 0; ut < 2; ++ut){
          #pragma unroll
          for (int r = 0; r < 4; ++r){
            int m = mt * 16 + q * 4 + r;
            float yt = yt_s[m];
            float iv = pA[mt][0][ut][r] + yt * wih_r[0][ut] + br[0][ut];
            float fv = pA[mt][1][ut][r] + yt * wih_r[1][ut] + br[1][ut];
            iact[mt][ut][r] = sigm(iv);
            cst[mt][ut][r] = sigm(fv) * cst[mt][ut][r];   // fterm; old cst dead
          }
        }
      }
    }
    // ---- GEMM-6 pass B: gates g,o (K=256) ----
    f32x4 pB[2][2][2];
    #pragma unroll
    for (int mt = 0; mt < 2; ++mt)
      for (int g = 0; g < 2; ++g)
        for (int ut = 0; ut < 2; ++ut) pB[mt][g][ut] = vzero;
    for (int kc = 0; kc < 8; ++kc){
      bf16x8 a0 = *(const bf16x8*)&A_s[ln * 552 + kc * 32 + q * 8];
      bf16x8 a1 = *(const bf16x8*)&A_s[(16 + ln) * 552 + kc * 32 + q * 8];
      #pragma unroll
      for (int g = 0; g < 2; ++g){
        #pragma unroll
        for (int ut = 0; ut < 2; ++ut){
          bf16x8 bb = W6v[(((g + 2) * 16 + wv * 2 + ut) * 8 + kc) * 64 + lane];
          pB[0][g][ut] = __builtin_amdgcn_mfma_f32_16x16x32_bf16(a0, bb, pB[0][g][ut], 0, 0, 0);
          pB[1][g][ut] = __builtin_amdgcn_mfma_f32_16x16x32_bf16(a1, bb, pB[1][g][ut], 0, 0, 0);
        }
      }
    }
    __syncthreads();   // E: all A_s reads done before pointwise writes
    // ---- LSTM pointwise: c2 = fterm + iact*tanh(gv); d2 = sigm(ov)*tanh(c2) ----
    #pragma unroll
    for (int mt = 0; mt < 2; ++mt){
      #pragma unroll
      for (int ut = 0; ut < 2; ++ut){
        #pragma unroll
        for (int r = 0; r < 4; ++r){
          int m = mt * 16 + q * 4 + r, u = u0 + ut * 16;
          float yt = yt_s[m];
          float gv = pB[mt][0][ut][r] + yt * wih_r[2][ut] + br[2][ut];
          float ov = pB[mt][1][ut][r] + yt * wih_r[3][ut] + br[3][ut];
          float c2 = cst[mt][ut][r] + iact[mt][ut][r] * ftanh(gv);
          float d2 = sigm(ov) * ftanh(c2);
          cst[mt][ut][r] = c2;
          A_s[m * 552 + u] = f2bf(d2);
          A_s[m * 552 + 256 + u] = f2bf(c2);
        }
      }
    }
    __syncthreads();   // F: A_s stable for next step's GEMMs
  }
  // ---- y_pred = d.ffw[:256] + sum_t beta*cff + ffb ----
  {
    int m = tid >> 4, l16 = tid & 15;
    float part = 0.f;
    #pragma unroll
    for (int it = 0; it < 16; ++it){
      int h = l16 + it * 16;
      part += bf2f(A_s[m * 552 + h]) * ldf(ffw, h, sh, ad);
    }
    part += __shfl_xor(part, 1); part += __shfl_xor(part, 2);
    part += __shfl_xor(part, 4); part += __shfl_xor(part, 8);
    if (l16 == 0){
      float cx = 0.f;
      #pragma unroll
      for (int tt = 0; tt < 15; ++tt) cx += beta_s[m * 15 + tt] * cff_s[m * 15 + tt];
      float v = part + cx + ldf(ffb, 0, sh, ad);
      if (F) ((u16*)outp)[b0 + m] = f2bf(v);
      else   ((float*)outp)[b0 + m] = v;
    }
  }
}

// ---------------------------------------------------------------------------
extern "C" void kernel_launch(void* const* d_in, const int* in_sizes, int n_in,
                              void* d_out, int out_size, void* d_ws, size_t ws_size,
                              hipStream_t stream){
  (void)in_sizes; (void)n_in; (void)out_size; (void)ws_size;
  const void* X      = d_in[0];
  const void* y_prev = d_in[1];
  const void* e1w    = d_in[2];
  const void* e2w    = d_in[4];
  const void* l2_wih = d_in[9];
  const void* l2_whh = d_in[10];
  const void* l2_b   = d_in[11];
  const void* da1w   = d_in[12];
  const void* da1b   = d_in[13];
  const void* da2w   = d_in[14];
  const void* dl_wih = d_in[16];
  const void* dl_whh = d_in[17];
  const void* dl_b   = d_in[18];
  const void* fc_w   = d_in[19];
  const void* fc_b   = d_in[20];
  const void* ff_w   = d_in[21];
  const void* ff_b   = d_in[22];

  char* ws = (char*)d_ws;
  float* wmul = (float*)(ws + 0);              // 8192*96*4      = 3,145,728
  u16* Wenc   = (u16*)(ws + 3145728);          // 360448*2       =   720,896
  u16* Wd6    = (u16*)(ws + 3866624);          // 262144*2       =   524,288
  u16* Wd1    = (u16*)(ws + 4390912);          // 131072*2       =   262,144
  u16* Wxp    = (u16*)(ws + 4653056);          // 65536*2        =   131,072
  float* cfg  = (float*)(ws + 4784128);        // 8192*15*4      =   491,520
  float* cffg = (float*)(ws + 5275648);        // 8192*15*4      =   491,520
  u16* xp     = (u16*)(ws + 5767168);          // 8192*15*256*2  = 62,914,560
  int* flagp  = (int*)(ws + 68681728);         // 4 B; total ws use ~68.7 MB

  k_detect<<<dim3(1),   dim3(64),  0, stream>>>((const u16*)X, flagp);
  k_attn <<<dim3(2048), dim3(256), 0, stream>>>(X, e1w, e2w, wmul, flagp);
  k_pack <<<dim3(3200), dim3(256), 0, stream>>>(l2_wih, l2_whh, dl_whh, da1w,
                                                Wenc, Wd6, Wd1, Wxp, flagp);
  k_enc  <<<dim3(256),  dim3(512), 0, stream>>>(X, wmul, Wenc, Wxp, l2_b, da1b,
                                                fc_w, ff_w, xp, cfg, cffg, flagp);
  k_dec  <<<dim3(256),  dim3(512), 0, stream>>>(xp, cfg, cffg, y_prev, Wd1, Wd6, da2w,
                                                dl_wih, dl_b, fc_w, fc_b, ff_w, ff_b,
                                                d_out, flagp);
}

// Round 7
// 2162.360 us; speedup vs baseline: 1.1778x; 1.1778x over previous
//
#include <hip/hip_runtime.h>

// DSTP-RNN fused implementation for MI355X (gfx950).
// Structural facts (proved from the reference):
//  * encoder softmaxes over D are invariant to the recurrent-state terms -> a1,a2 precomputable
//  * LSTM1 is dead (its state only feeds a cancelled softmax shift)
//  * decoder ctx is only used via ctx.fc_w and ctx.ff_w[256:] -> per-(b,t) scalars cf/cff
//  * all recurrences are independent per batch row -> per-tile kernels, no grid sync
// Dtype handling: harness hands fp32 (reference dtype) or bf16; k_detect sniffs and
// all raw-input reads use a branchless u16 load at (i<<sh)+ad.
// R7: compiler refuses >128 VGPRs for 512-thread blocks (R4/R5/R6 all pinned at 128,
// xq spilled -> 2.1 GB/dispatch scratch traffic). Pivot: k_dec goes to 16 rows/block
// (grid 512) with the xp slice LDS-resident (128 KB, loaded once, reused 15 steps).
// k_enc writes xp in [b][j][tt16] layout so the preload is one contiguous copy.
// xp_s banking: 513-uint4 row stride + c^(q&1) swizzle -> 2 lanes/bank (free).

typedef unsigned short u16;
using bf16x8 = __attribute__((ext_vector_type(8))) short;   // 8 bf16 = 4 VGPRs (MFMA A/B frag)
using f32x4  = __attribute__((ext_vector_type(4))) float;   // MFMA C/D frag

__device__ __forceinline__ float bf2f(u16 u){
  union { unsigned int i; float f; } v; v.i = ((unsigned int)u) << 16; return v.f;
}
__device__ __forceinline__ u16 f2bf(float f){
  union { float f; unsigned int i; } v; v.f = f;
  unsigned int x = v.i;
  return (u16)((x + 0x7fffu + ((x >> 16) & 1u)) >> 16);  // RNE
}
// raw bf16 bits of input element i under dtype mode (sh,ad)
__device__ __forceinline__ u16 ldraw(const void* p, size_t i, int sh, int ad){
  return *(const u16*)((const char*)p + (i << sh) + ad);
}
__device__ __forceinline__ float ldf(const void* p, size_t i, int sh, int ad){
  return bf2f(ldraw(p, i, sh, ad));
}
__device__ __forceinline__ float sigm(float x){ return __builtin_amdgcn_rcpf(1.f + __expf(-x)); }
__device__ __forceinline__ float ftanh(float x){
  float e = __expf(2.f * x);
  return 1.f - 2.f * __builtin_amdgcn_rcpf(e + 1.f);
}

// ---------------------------------------------------------------------------
// k_detect: decide input dtype. flag=1 -> bf16, flag=0 -> fp32. 64 lanes check
// 128 even-index u16s of X in parallel (bf16 N(0,1) stays in exponent [64,191]).
// ---------------------------------------------------------------------------
__global__ void k_detect(const u16* __restrict__ Xu, int* __restrict__ flag){
  int lane = threadIdx.x & 63;
  u16 a = Xu[2 * lane], b = Xu[2 * (lane + 64)];
  int exa = (a >> 7) & 0xFF, exb = (b >> 7) & 0xFF;
  bool bad = !(a == 0 || a == 0x8000 || (exa >= 64 && exa <= 191)) ||
             !(b == 0 || b == 0x8000 || (exb >= 64 && exb <= 191));
  unsigned long long bal = __ballot(bad);
  if (threadIdx.x == 0 && blockIdx.x == 0) *flag = (bal == 0ull) ? 1 : 0;
}

// ---------------------------------------------------------------------------
// k_attn: wmul[b][d] = a1[b][d]*a2[b][d], d in [0,96) (81 valid, pad 0), fp32.
// ---------------------------------------------------------------------------
__global__ __launch_bounds__(256) void k_attn(const void* __restrict__ X,
    const void* __restrict__ e1w, const void* __restrict__ e2w,
    float* __restrict__ wmul, const int* __restrict__ flagp){
  int F = *flagp, sh = 2 - F, ad = F ? 0 : 2;
  int wv = threadIdx.x >> 6, lane = threadIdx.x & 63;
  int b = blockIdx.x * 4 + wv;
  size_t xb0 = (size_t)b * (15 * 81);
  float s1a = 0.f, s1b = 0.f, s2a = 0.f, s2b = 0.f;
  int d1 = 64 + lane;
  bool v1 = d1 < 81;
  #pragma unroll
  for (int t = 0; t < 15; ++t){
    float w1 = ldf(e1w, 512 + t, sh, ad), w2 = ldf(e2w, 512 + t, sh, ad); // w1x,w2x at [2*He:]
    float xa = ldf(X, xb0 + t * 81 + lane, sh, ad);
    float xb = v1 ? ldf(X, xb0 + t * 81 + d1, sh, ad) : 0.f;
    s1a += w1 * xa; s1b += w1 * xb;
    s2a += w2 * xa; s2b += w2 * xb;
  }
  if (!v1){ s1b = -1e30f; s2b = -1e30f; }
  float m1 = fmaxf(s1a, s1b), m2 = fmaxf(s2a, s2b);
  for (int o = 32; o; o >>= 1){ m1 = fmaxf(m1, __shfl_xor(m1, o)); m2 = fmaxf(m2, __shfl_xor(m2, o)); }
  float e1a = __expf(s1a - m1), e1b = v1 ? __expf(s1b - m1) : 0.f;
  float e2a = __expf(s2a - m2), e2b = v1 ? __expf(s2b - m2) : 0.f;
  float S1 = e1a + e1b, S2 = e2a + e2b;
  for (int o = 32; o; o >>= 1){ S1 += __shfl_xor(S1, o); S2 += __shfl_xor(S2, o); }
  float inv = 1.f / (S1 * S2);
  wmul[(size_t)b * 96 + lane] = e1a * e2a * inv;
  if (lane < 32) wmul[(size_t)b * 96 + d1] = v1 ? e1b * e2b * inv : 0.f;
}

// ---------------------------------------------------------------------------
// k_pack: repack weights into MFMA B-fragment order. Frag (nt,kc): element
// ((nt*KC+kc)*64+lane)*8+j holds W[n=nt*16+(lane&15)][k=kc*32+(lane>>4)*8+j].
// ---------------------------------------------------------------------------
__global__ __launch_bounds__(256) void k_pack(const void* __restrict__ l2_wih,
    const void* __restrict__ l2_whh, const void* __restrict__ dl_whh,
    const void* __restrict__ da1w, u16* __restrict__ Wenc, u16* __restrict__ Wd6,
    u16* __restrict__ Wd1, u16* __restrict__ Wxp, const int* __restrict__ flagp){
  int F = *flagp, sh = 2 - F, ad = F ? 0 : 2;
  int e = blockIdx.x * 256 + threadIdx.x;
  if (e >= 819200) return;
  if (e < 360448){
    int j = e & 7, lane = (e >> 3) & 63, fc = e >> 9;
    int nt = fc / 11, kc = fc - nt * 11;
    int n = nt * 16 + (lane & 15), k = kc * 32 + (lane >> 4) * 8 + j;
    u16 v = 0;
    if (k < 81) v = ldraw(l2_wih, n * 81 + k, sh, ad);
    else if (k >= 96) v = ldraw(l2_whh, n * 256 + (k - 96), sh, ad);
    Wenc[e] = v;
  } else if (e < 360448 + 262144){
    int e2 = e - 360448;
    int j = e2 & 7, lane = (e2 >> 3) & 63, fc = e2 >> 9;
    int kc = fc & 7, nt = fc >> 3;
    int n = nt * 16 + (lane & 15), k = kc * 32 + (lane >> 4) * 8 + j;
    Wd6[e2] = ldraw(dl_whh, n * 256 + k, sh, ad);
  } else if (e < 360448 + 262144 + 131072){
    int e3 = e - (360448 + 262144);
    int j = e3 & 7, lane = (e3 >> 3) & 63, fc = e3 >> 9;
    int kc = fc & 15, nt = fc >> 4;
    int n = nt * 16 + (lane & 15), k = kc * 32 + (lane >> 4) * 8 + j;
    Wd1[e3] = ldraw(da1w, n * 768 + k, sh, ad);
  } else {
    int e4 = e - (360448 + 262144 + 131072);
    int j = e4 & 7, lane = (e4 >> 3) & 63, fc = e4 >> 9;
    int kc = fc & 7, nt = fc >> 3;
    int n = nt * 16 + (lane & 15), k = kc * 32 + (lane >> 4) * 8 + j;
    Wxp[e4] = ldraw(da1w, n * 768 + 512 + k, sh, ad);
  }
}

// ---------------------------------------------------------------------------
// k_enc: LSTM2 over 15 steps, 32 rows/block (grid 256), 8 waves. Per step the
// LSTM pointwise is followed by xp_t = h_t @ W1x^T + d_a1_b plus scalars
// cf=h.fc_w, cff=h.ffw[256:]. xp is written TRANSPOSED: xp[(b*256+j)*16 + t]
// so k_dec's per-block slice is one contiguous 128 KB range.
// ---------------------------------------------------------------------------
__global__ __launch_bounds__(512) void k_enc(const void* __restrict__ X,
    const float* __restrict__ wmul, const u16* __restrict__ Wenc,
    const u16* __restrict__ Wxp, const void* __restrict__ l2_b,
    const void* __restrict__ da1b, const void* __restrict__ fcw,
    const void* __restrict__ ffw, u16* __restrict__ xp,
    float* __restrict__ cfg, float* __restrict__ cffg,
    const int* __restrict__ flagp){
  __shared__ u16 A_s[32 * 360];        // [m][k]: k<96 = x_tilde2 (pad0), k in [96,352) = h
  __shared__ float w_s[32 * 96];
  __shared__ float cf_s[32], cff_s[32];
  int F = *flagp, sh = 2 - F, ad = F ? 0 : 2;
  int tid = threadIdx.x, wv = tid >> 6, lane = tid & 63, q = lane >> 4, ln = lane & 15;
  int b0 = blockIdx.x * 32;
  for (int i = tid; i < 32 * 96; i += 512){
    int m = i / 96;
    w_s[i] = wmul[(size_t)(b0 + m) * 96 + (i - m * 96)];
  }
  for (int i = tid; i < 32 * 360; i += 512) A_s[i] = 0;
  int u0 = wv * 32 + ln;
  float bi[2], bff[2], bg[2], bo[2], fcr[2], ffr[2], dbr[2];
  #pragma unroll
  for (int ut = 0; ut < 2; ++ut){
    int u = u0 + ut * 16;
    bi[ut]  = ldf(l2_b, u, sh, ad);        bff[ut] = ldf(l2_b, 256 + u, sh, ad);
    bg[ut]  = ldf(l2_b, 512 + u, sh, ad);  bo[ut]  = ldf(l2_b, 768 + u, sh, ad);
    fcr[ut] = ldf(fcw, u, sh, ad);         ffr[ut] = ldf(ffw, 256 + u, sh, ad);
    dbr[ut] = ldf(da1b, u, sh, ad);
  }
  float cst[2][2][4];
  #pragma unroll
  for (int a = 0; a < 2; ++a)
    for (int c = 0; c < 2; ++c)
      for (int r = 0; r < 4; ++r) cst[a][c][r] = 0.f;
  __syncthreads();
  const bf16x8* Wv  = (const bf16x8*)Wenc;
  const bf16x8* Wxv = (const bf16x8*)Wxp;
  const f32x4 vzero = {0.f, 0.f, 0.f, 0.f};
  for (int t = 0; t < 15; ++t){
    // ---- stage x_tilde2 = (a1*a2) .* x_t into A[:, 0:96) ----
    for (int i = tid; i < 32 * 96; i += 512){
      int m = i / 96, dd = i - m * 96;
      float v = 0.f;
      if (dd < 81) v = ldf(X, (size_t)(b0 + m) * 1215 + t * 81 + dd, sh, ad) * w_s[i];
      A_s[m * 360 + dd] = f2bf(v);
    }
    __syncthreads();   // s1
    if (tid < 64){ if (tid < 32) cf_s[tid] = 0.f; else cff_s[tid - 32] = 0.f; }
    // ---- gates GEMM: K=352 ----
    f32x4 acc[2][4][2];
    #pragma unroll
    for (int mt = 0; mt < 2; ++mt)
      for (int g = 0; g < 4; ++g)
        for (int ut = 0; ut < 2; ++ut) acc[mt][g][ut] = vzero;
    for (int kc = 0; kc < 11; ++kc){
      bf16x8 a0 = *(const bf16x8*)&A_s[ln * 360 + kc * 32 + q * 8];
      bf16x8 a1 = *(const bf16x8*)&A_s[(16 + ln) * 360 + kc * 32 + q * 8];
      #pragma unroll
      for (int g = 0; g < 4; ++g){
        #pragma unroll
        for (int ut = 0; ut < 2; ++ut){
          int ntg = g * 16 + wv * 2 + ut;
          bf16x8 bb = Wv[(ntg * 11 + kc) * 64 + lane];
          acc[0][g][ut] = __builtin_amdgcn_mfma_f32_16x16x32_bf16(a0, bb, acc[0][g][ut], 0, 0, 0);
          acc[1][g][ut] = __builtin_amdgcn_mfma_f32_16x16x32_bf16(a1, bb, acc[1][g][ut], 0, 0, 0);
        }
      }
    }
    __syncthreads();   // s2
    // ---- LSTM pointwise; h -> A_s[.,96+u]; cf/cff partial reductions ----
    #pragma unroll
    for (int mt = 0; mt < 2; ++mt){
      #pragma unroll
      for (int r = 0; r < 4; ++r){
        int m = mt * 16 + q * 4 + r;
        float pf = 0.f, pff = 0.f;
        #pragma unroll
        for (int ut = 0; ut < 2; ++ut){
          int u = u0 + ut * 16;
          float iv = acc[mt][0][ut][r] + bi[ut];
          float fv = acc[mt][1][ut][r] + bff[ut];
          float gv = acc[mt][2][ut][r] + bg[ut];
          float ov = acc[mt][3][ut][r] + bo[ut];
          float c2 = sigm(fv) * cst[mt][ut][r] + sigm(iv) * ftanh(gv);
          float h2 = sigm(ov) * ftanh(c2);
          cst[mt][ut][r] = c2;
          A_s[m * 360 + 96 + u] = f2bf(h2);
          pf  += h2 * fcr[ut];
          pff += h2 * ffr[ut];
        }
        pf  += __shfl_xor(pf, 1);  pf  += __shfl_xor(pf, 2);
        pf  += __shfl_xor(pf, 4);  pf  += __shfl_xor(pf, 8);
        pff += __shfl_xor(pff, 1); pff += __shfl_xor(pff, 2);
        pff += __shfl_xor(pff, 4); pff += __shfl_xor(pff, 8);
        if (ln == 0){ atomicAdd(&cf_s[m], pf); atomicAdd(&cff_s[m], pff); }
      }
    }
    __syncthreads();   // s3
    // ---- xp GEMM: xp_t[m][j] = h_t[m][:] @ W1x^T + da1b, K=256 ----
    f32x4 xpa[2][2];
    #pragma unroll
    for (int mt = 0; mt < 2; ++mt)
      for (int ut = 0; ut < 2; ++ut) xpa[mt][ut] = vzero;
    for (int kc = 0; kc < 8; ++kc){
      bf16x8 a0 = *(const bf16x8*)&A_s[ln * 360 + 96 + kc * 32 + q * 8];
      bf16x8 a1 = *(const bf16x8*)&A_s[(16 + ln) * 360 + 96 + kc * 32 + q * 8];
      #pragma unroll
      for (int ut = 0; ut < 2; ++ut){
        bf16x8 bb = Wxv[((wv * 2 + ut) * 8 + kc) * 64 + lane];
        xpa[0][ut] = __builtin_amdgcn_mfma_f32_16x16x32_bf16(a0, bb, xpa[0][ut], 0, 0, 0);
        xpa[1][ut] = __builtin_amdgcn_mfma_f32_16x16x32_bf16(a1, bb, xpa[1][ut], 0, 0, 0);
      }
    }
    #pragma unroll
    for (int mt = 0; mt < 2; ++mt){
      #pragma unroll
      for (int ut = 0; ut < 2; ++ut){
        int j = u0 + ut * 16;
        #pragma unroll
        for (int r = 0; r < 4; ++r){
          int m = mt * 16 + q * 4 + r;
          xp[((size_t)(b0 + m) * 256 + j) * 16 + t] = f2bf(xpa[mt][ut][r] + dbr[ut]);
        }
      }
    }
    if (tid < 32){
      cfg [(size_t)(b0 + tid) * 15 + t] = cf_s[tid];
      cffg[(size_t)(b0 + tid) * 15 + t] = cff_s[tid];
    }
  }
}

// ---------------------------------------------------------------------------
// k_dec: decoder, 16 rows/block (grid 512), 15 steps, 1 block/CU (LDS 153 KB).
// The block's xp slice [16 rows][256 j][16 tt] lives in LDS (one contiguous
// coalesced 128 KB preload; layout row stride 513 uint4 + c^(q&1) swizzle ->
// conflict-free b128 reads). Score phase: regs + LDS only. Single-pass GEMM-6
// (M=16 -> 32 accum regs); peak live VGPRs ~110 < 128 -> no scratch.
// ---------------------------------------------------------------------------
__global__ __launch_bounds__(512) void k_dec(const u16* __restrict__ xpv,
    const float* __restrict__ cfg, const float* __restrict__ cffg,
    const void* __restrict__ y_prev,
    const u16* __restrict__ Wd1, const u16* __restrict__ Wd6,
    const void* __restrict__ da2w, const void* __restrict__ dl_wih,
    const void* __restrict__ dl_b, const void* __restrict__ fcw,
    const void* __restrict__ fcb, const void* __restrict__ ffw,
    const void* __restrict__ ffb, void* __restrict__ outp,
    const int* __restrict__ flagp){
  __shared__ u16 A_s[16 * 552];          // [m][k]: k<256 = d, k in [256,512) = c (bf16)
  __shared__ uint4 xp4_s[16 * 513];      // [m][j][2 uint4] row-padded + swizzled
  __shared__ float score_s[240], beta_s[240], cf_s[240], cff_s[240];
  __shared__ float yt_s[16];
  int F = *flagp, sh = 2 - F, ad = F ? 0 : 2;
  int tid = threadIdx.x, wv = tid >> 6, lane = tid & 63, q = lane >> 4, ln = lane & 15;
  int b0 = blockIdx.x * 16;
  int u0 = wv * 32 + ln;
  float w2v[2], wih_r[4][2], br[4][2];
  #pragma unroll
  for (int ut = 0; ut < 2; ++ut){
    int u = u0 + ut * 16;
    w2v[ut] = ldf(da2w, u, sh, ad);
    #pragma unroll
    for (int g = 0; g < 4; ++g){
      wih_r[g][ut] = ldf(dl_wih, g * 256 + u, sh, ad);
      br[g][ut]   = ldf(dl_b, g * 256 + u, sh, ad);
    }
  }
  float fcw256 = ldf(fcw, 256, sh, ad), fcbv = ldf(fcb, 0, sh, ad);
  float cst[2][4];
  #pragma unroll
  for (int c = 0; c < 2; ++c)
    for (int r = 0; r < 4; ++r) cst[c][r] = 0.f;
  for (int i = tid; i < 16 * 552; i += 512) A_s[i] = 0;
  if (tid < 240){
    int row = tid / 15, tt = tid - row * 15;
    score_s[tid] = 0.f;
    cf_s [tid] = cfg [(size_t)(b0 + row) * 15 + tt];
    cff_s[tid] = cffg[(size_t)(b0 + row) * 15 + tt];
  }
  // ---- xp preload: global [b][j][16tt] slice is contiguous 128 KB ----
  {
    const uint4* gp = (const uint4*)(xpv + (size_t)b0 * 4096);  // 16 rows*256*16 u16
    #pragma unroll
    for (int rep = 0; rep < 16; ++rep){
      int i4 = tid + rep * 512;            // 8192 uint4 total
      int m = i4 >> 9, inner = i4 & 511;   // inner = j*2 + c
      int j = inner >> 1, c = inner & 1;
      int cp = c ^ ((m >> 2) & 1);         // bank swizzle
      xp4_s[m * 513 + j * 2 + cp] = gp[i4];
    }
  }
  __syncthreads();
  const bf16x8* W1v = (const bf16x8*)Wd1;
  const bf16x8* W6v = (const bf16x8*)Wd6;
  const f32x4 vzero = {0.f, 0.f, 0.f, 0.f};
  for (int t = 0; t < 15; ++t){
    // ---- GEMM-1: proj[m][j] over K=512 ([d|c]), M=16 ----
    f32x4 p1[2];
    #pragma unroll
    for (int ut = 0; ut < 2; ++ut) p1[ut] = vzero;
    for (int kc = 0; kc < 16; ++kc){
      bf16x8 a0 = *(const bf16x8*)&A_s[ln * 552 + kc * 32 + q * 8];
      #pragma unroll
      for (int ut = 0; ut < 2; ++ut){
        bf16x8 bb = W1v[((wv * 2 + ut) * 16 + kc) * 64 + lane];
        p1[ut] = __builtin_amdgcn_mfma_f32_16x16x32_bf16(a0, bb, p1[ut], 0, 0, 0);
      }
    }
    // ---- score[m][tt] = sum_j w2[j]*tanh(xp[m][tt][j] + proj[m][j]) ----
    #pragma unroll
    for (int r = 0; r < 4; ++r){
      int m = q * 4 + r;
      float sc[15];
      #pragma unroll
      for (int tt = 0; tt < 15; ++tt) sc[tt] = 0.f;
      #pragma unroll
      for (int ut = 0; ut < 2; ++ut){
        float p = p1[ut][r];
        int base = m * 513 + (u0 + ut * 16) * 2;
        uint4 c0 = xp4_s[base + (q & 1)];        // logical c=0: tt 0..7
        uint4 c1 = xp4_s[base + 1 - (q & 1)];    // logical c=1: tt 8..15
        unsigned int w[8] = {c0.x, c0.y, c0.z, c0.w, c1.x, c1.y, c1.z, c1.w};
        #pragma unroll
        for (int p8 = 0; p8 < 8; ++p8){
          sc[2 * p8] += w2v[ut] * ftanh(p + bf2f((u16)(w[p8] & 0xffffu)));
          if (p8 < 7)
            sc[2 * p8 + 1] += w2v[ut] * ftanh(p + bf2f((u16)(w[p8] >> 16)));
        }
      }
      #pragma unroll
      for (int tt = 0; tt < 15; ++tt){
        float v = sc[tt];
        v += __shfl_xor(v, 1); v += __shfl_xor(v, 2);
        v += __shfl_xor(v, 4); v += __shfl_xor(v, 8);
        if (ln == 0) atomicAdd(&score_s[m * 15 + tt], v);
      }
    }
    __syncthreads();   // B: score atomics complete
    // ---- softmax over t + y_tilde (uses cf); re-zero score_s for next step ----
    if (tid < 16){
      float s[15]; float mx = -1e30f;
      #pragma unroll
      for (int tt = 0; tt < 15; ++tt){ s[tt] = score_s[tid * 15 + tt]; mx = fmaxf(mx, s[tt]); }
      float sum = 0.f;
      #pragma unroll
      for (int tt = 0; tt < 15; ++tt){ s[tt] = __expf(s[tt] - mx); sum += s[tt]; }
      float inv = 1.f / sum;
      float yt = fcbv + ldf(y_prev, (size_t)(b0 + tid) * 15 + t, sh, ad) * fcw256;
      #pragma unroll
      for (int tt = 0; tt < 15; ++tt){
        float bv = s[tt] * inv;
        beta_s[tid * 15 + tt] = bv;
        score_s[tid * 15 + tt] = 0.f;
        yt += bv * cf_s[tid * 15 + tt];
      }
      yt_s[tid] = yt;
    }
    __syncthreads();   // C: beta/yt/zeroed-score visible
    // ---- GEMM-6: gates = d @ dl_whh^T (K=256), M=16, single pass ----
    f32x4 p6[4][2];
    #pragma unroll
    for (int g = 0; g < 4; ++g)
      for (int ut = 0; ut < 2; ++ut) p6[g][ut] = vzero;
    for (int kc = 0; kc < 8; ++kc){
      bf16x8 a0 = *(const bf16x8*)&A_s[ln * 552 + kc * 32 + q * 8];
      #pragma unroll
      for (int g = 0; g < 4; ++g){
        #pragma unroll
        for (int ut = 0; ut < 2; ++ut){
          bf16x8 bb = W6v[((g * 16 + wv * 2 + ut) * 8 + kc) * 64 + lane];
          p6[g][ut] = __builtin_amdgcn_mfma_f32_16x16x32_bf16(a0, bb, p6[g][ut], 0, 0, 0);
        }
      }
    }
    __syncthreads();   // E: A_s reads done before pointwise writes
    // ---- LSTM pointwise: + y_tilde*dl_wih + dl_b ----
    #pragma unroll
    for (int ut = 0; ut < 2; ++ut){
      #pragma unroll
      for (int r = 0; r < 4; ++r){
        int m = q * 4 + r, u = u0 + ut * 16;
        float yt = yt_s[m];
        float iv = p6[0][ut][r] + yt * wih_r[0][ut] + br[0][ut];
        float fv = p6[1][ut][r] + yt * wih_r[1][ut] + br[1][ut];
        float gv = p6[2][ut][r] + yt * wih_r[2][ut] + br[2][ut];
        float ov = p6[3][ut][r] + yt * wih_r[3][ut] + br[3][ut];
        float c2 = sigm(fv) * cst[ut][r] + sigm(iv) * ftanh(gv);
        float d2 = sigm(ov) * ftanh(c2);
        cst[ut][r] = c2;
        A_s[m * 552 + u] = f2bf(d2);
        A_s[m * 552 + 256 + u] = f2bf(c2);
      }
    }
    __syncthreads();   // Fb: A_s stable for next step's GEMMs
  }
  // ---- y_pred = d.ffw[:256] + sum_t beta*cff + ffb ----
  if (tid < 256){
    int m = tid >> 4, l16 = tid & 15;
    float part = 0.f;
    #pragma unroll
    for (int it = 0; it < 16; ++it){
      int h = l16 + it * 16;
      part += bf2f(A_s[m * 552 + h]) * ldf(ffw, h, sh, ad);
    }
    part += __shfl_xor(part, 1); part += __shfl_xor(part, 2);
    part += __shfl_xor(part, 4); part += __shfl_xor(part, 8);
    if (l16 == 0){
      float cx = 0.f;
      #pragma unroll
      for (int tt = 0; tt < 15; ++tt) cx += beta_s[m * 15 + tt] * cff_s[m * 15 + tt];
      float v = part + cx + ldf(ffb, 0, sh, ad);
      if (F) ((u16*)outp)[b0 + m] = f2bf(v);
      else   ((float*)outp)[b0 + m] = v;
    }
  }
}

// ---------------------------------------------------------------------------
extern "C" void kernel_launch(void* const* d_in, const int* in_sizes, int n_in,
                              void* d_out, int out_size, void* d_ws, size_t ws_size,
                              hipStream_t stream){
  (void)in_sizes; (void)n_in; (void)out_size; (void)ws_size;
  const void* X      = d_in[0];
  const void* y_prev = d_in[1];
  const void* e1w    = d_in[2];
  const void* e2w    = d_in[4];
  const void* l2_wih = d_in[9];
  const void* l2_whh = d_in[10];
  const void* l2_b   = d_in[11];
  const void* da1w   = d_in[12];
  const void* da1b   = d_in[13];
  const void* da2w   = d_in[14];
  const void* dl_wih = d_in[16];
  const void* dl_whh = d_in[17];
  const void* dl_b   = d_in[18];
  const void* fc_w   = d_in[19];
  const void* fc_b   = d_in[20];
  const void* ff_w   = d_in[21];
  const void* ff_b   = d_in[22];

  char* ws = (char*)d_ws;
  float* wmul = (float*)(ws + 0);              // 8192*96*4       = 3,145,728
  u16* Wenc   = (u16*)(ws + 3145728);          // 360448*2        =   720,896
  u16* Wd6    = (u16*)(ws + 3866624);          // 262144*2        =   524,288
  u16* Wd1    = (u16*)(ws + 4390912);          // 131072*2        =   262,144
  u16* Wxp    = (u16*)(ws + 4653056);          // 65536*2         =   131,072
  float* cfg  = (float*)(ws + 4784128);        // 8192*15*4       =   491,520
  float* cffg = (float*)(ws + 5275648);        // 8192*15*4       =   491,520
  u16* xp     = (u16*)(ws + 5767168);          // 8192*256*16*2   = 67,108,864
  int* flagp  = (int*)(ws + 72876032);         // 4 B; total ws ~72.9 MB

  k_detect<<<dim3(1),   dim3(64),  0, stream>>>((const u16*)X, flagp);
  k_attn <<<dim3(2048), dim3(256), 0, stream>>>(X, e1w, e2w, wmul, flagp);
  k_pack <<<dim3(3200), dim3(256), 0, stream>>>(l2_wih, l2_whh, dl_whh, da1w,
                                                Wenc, Wd6, Wd1, Wxp, flagp);
  k_enc  <<<dim3(256),  dim3(512), 0, stream>>>(X, wmul, Wenc, Wxp, l2_b, da1b,
                                                fc_w, ff_w, xp, cfg, cffg, flagp);
  k_dec  <<<dim3(512),  dim3(512), 0, stream>>>(xp, cfg, cffg, y_prev, Wd1, Wd6, da2w,
                                                dl_wih, dl_b, fc_w, fc_b, ff_w, ff_b,
                                                d_out, flagp);
}

// Round 8
// 1610.764 us; speedup vs baseline: 1.5811x; 1.3424x over previous
//
#include <hip/hip_runtime.h>

// DSTP-RNN fused implementation for MI355X (gfx950).
// Structural facts (proved from the reference):
//  * encoder softmaxes over D are invariant to the recurrent-state terms -> a1,a2 precomputable
//  * LSTM1 is dead (its state only feeds a cancelled softmax shift)
//  * decoder ctx is only used via ctx.fc_w and ctx.ff_w[256:] -> per-(b,t) scalars cf/cff
//  * all recurrences are independent per batch row -> per-tile kernels, no grid sync
// Dtype handling: harness hands fp32 (reference dtype) or bf16; k_detect sniffs and
// all raw-input reads use a branchless u16 load at (i<<sh)+ad.
// R8: k_dec score phase rebuilt — proj goes to LDS (bf16), one thread per
// (m,tt,jhalf) with a scalar accumulator over 128 j (ds_read_b128 of xp/proj/w2).
// No register arrays, no shfl reductions, no LDS atomics (R3-R7 all carried
// ~300 MB of mystery scratch WRITE_SIZE + 5.9M identical LDS-conflict counts —
// attributed to the old score phase's sc[15] + atomic pattern). k_enc gates GEMM
// split into two 2-gate passes (acc 64->32 regs, spill insurance).

typedef unsigned short u16;
using bf16x8 = __attribute__((ext_vector_type(8))) short;   // 8 bf16 = 4 VGPRs (MFMA A/B frag)
using f32x4  = __attribute__((ext_vector_type(4))) float;   // MFMA C/D frag

__device__ __forceinline__ float bf2f(u16 u){
  union { unsigned int i; float f; } v; v.i = ((unsigned int)u) << 16; return v.f;
}
__device__ __forceinline__ u16 f2bf(float f){
  union { float f; unsigned int i; } v; v.f = f;
  unsigned int x = v.i;
  return (u16)((x + 0x7fffu + ((x >> 16) & 1u)) >> 16);  // RNE
}
// raw bf16 bits of input element i under dtype mode (sh,ad)
__device__ __forceinline__ u16 ldraw(const void* p, size_t i, int sh, int ad){
  return *(const u16*)((const char*)p + (i << sh) + ad);
}
__device__ __forceinline__ float ldf(const void* p, size_t i, int sh, int ad){
  return bf2f(ldraw(p, i, sh, ad));
}
__device__ __forceinline__ float sigm(float x){ return __builtin_amdgcn_rcpf(1.f + __expf(-x)); }
__device__ __forceinline__ float ftanh(float x){
  float e = __expf(2.f * x);
  return 1.f - 2.f * __builtin_amdgcn_rcpf(e + 1.f);
}

// ---------------------------------------------------------------------------
// k_detect: decide input dtype. flag=1 -> bf16, flag=0 -> fp32.
// ---------------------------------------------------------------------------
__global__ void k_detect(const u16* __restrict__ Xu, int* __restrict__ flag){
  int lane = threadIdx.x & 63;
  u16 a = Xu[2 * lane], b = Xu[2 * (lane + 64)];
  int exa = (a >> 7) & 0xFF, exb = (b >> 7) & 0xFF;
  bool bad = !(a == 0 || a == 0x8000 || (exa >= 64 && exa <= 191)) ||
             !(b == 0 || b == 0x8000 || (exb >= 64 && exb <= 191));
  unsigned long long bal = __ballot(bad);
  if (threadIdx.x == 0 && blockIdx.x == 0) *flag = (bal == 0ull) ? 1 : 0;
}

// ---------------------------------------------------------------------------
// k_attn: wmul[b][d] = a1[b][d]*a2[b][d], d in [0,96) (81 valid, pad 0), fp32.
// ---------------------------------------------------------------------------
__global__ __launch_bounds__(256) void k_attn(const void* __restrict__ X,
    const void* __restrict__ e1w, const void* __restrict__ e2w,
    float* __restrict__ wmul, const int* __restrict__ flagp){
  int F = *flagp, sh = 2 - F, ad = F ? 0 : 2;
  int wv = threadIdx.x >> 6, lane = threadIdx.x & 63;
  int b = blockIdx.x * 4 + wv;
  size_t xb0 = (size_t)b * (15 * 81);
  float s1a = 0.f, s1b = 0.f, s2a = 0.f, s2b = 0.f;
  int d1 = 64 + lane;
  bool v1 = d1 < 81;
  #pragma unroll
  for (int t = 0; t < 15; ++t){
    float w1 = ldf(e1w, 512 + t, sh, ad), w2 = ldf(e2w, 512 + t, sh, ad); // w1x,w2x at [2*He:]
    float xa = ldf(X, xb0 + t * 81 + lane, sh, ad);
    float xb = v1 ? ldf(X, xb0 + t * 81 + d1, sh, ad) : 0.f;
    s1a += w1 * xa; s1b += w1 * xb;
    s2a += w2 * xa; s2b += w2 * xb;
  }
  if (!v1){ s1b = -1e30f; s2b = -1e30f; }
  float m1 = fmaxf(s1a, s1b), m2 = fmaxf(s2a, s2b);
  for (int o = 32; o; o >>= 1){ m1 = fmaxf(m1, __shfl_xor(m1, o)); m2 = fmaxf(m2, __shfl_xor(m2, o)); }
  float e1a = __expf(s1a - m1), e1b = v1 ? __expf(s1b - m1) : 0.f;
  float e2a = __expf(s2a - m2), e2b = v1 ? __expf(s2b - m2) : 0.f;
  float S1 = e1a + e1b, S2 = e2a + e2b;
  for (int o = 32; o; o >>= 1){ S1 += __shfl_xor(S1, o); S2 += __shfl_xor(S2, o); }
  float inv = 1.f / (S1 * S2);
  wmul[(size_t)b * 96 + lane] = e1a * e2a * inv;
  if (lane < 32) wmul[(size_t)b * 96 + d1] = v1 ? e1b * e2b * inv : 0.f;
}

// ---------------------------------------------------------------------------
// k_pack: repack weights into MFMA B-fragment order. Frag (nt,kc): element
// ((nt*KC+kc)*64+lane)*8+j holds W[n=nt*16+(lane&15)][k=kc*32+(lane>>4)*8+j].
// ---------------------------------------------------------------------------
__global__ __launch_bounds__(256) void k_pack(const void* __restrict__ l2_wih,
    const void* __restrict__ l2_whh, const void* __restrict__ dl_whh,
    const void* __restrict__ da1w, u16* __restrict__ Wenc, u16* __restrict__ Wd6,
    u16* __restrict__ Wd1, u16* __restrict__ Wxp, const int* __restrict__ flagp){
  int F = *flagp, sh = 2 - F, ad = F ? 0 : 2;
  int e = blockIdx.x * 256 + threadIdx.x;
  if (e >= 819200) return;
  if (e < 360448){
    int j = e & 7, lane = (e >> 3) & 63, fc = e >> 9;
    int nt = fc / 11, kc = fc - nt * 11;
    int n = nt * 16 + (lane & 15), k = kc * 32 + (lane >> 4) * 8 + j;
    u16 v = 0;
    if (k < 81) v = ldraw(l2_wih, n * 81 + k, sh, ad);
    else if (k >= 96) v = ldraw(l2_whh, n * 256 + (k - 96), sh, ad);
    Wenc[e] = v;
  } else if (e < 360448 + 262144){
    int e2 = e - 360448;
    int j = e2 & 7, lane = (e2 >> 3) & 63, fc = e2 >> 9;
    int kc = fc & 7, nt = fc >> 3;
    int n = nt * 16 + (lane & 15), k = kc * 32 + (lane >> 4) * 8 + j;
    Wd6[e2] = ldraw(dl_whh, n * 256 + k, sh, ad);
  } else if (e < 360448 + 262144 + 131072){
    int e3 = e - (360448 + 262144);
    int j = e3 & 7, lane = (e3 >> 3) & 63, fc = e3 >> 9;
    int kc = fc & 15, nt = fc >> 4;
    int n = nt * 16 + (lane & 15), k = kc * 32 + (lane >> 4) * 8 + j;
    Wd1[e3] = ldraw(da1w, n * 768 + k, sh, ad);
  } else {
    int e4 = e - (360448 + 262144 + 131072);
    int j = e4 & 7, lane = (e4 >> 3) & 63, fc = e4 >> 9;
    int kc = fc & 7, nt = fc >> 3;
    int n = nt * 16 + (lane & 15), k = kc * 32 + (lane >> 4) * 8 + j;
    Wxp[e4] = ldraw(da1w, n * 768 + 512 + k, sh, ad);
  }
}

// ---------------------------------------------------------------------------
// k_enc: LSTM2 over 15 steps, 32 rows/block (grid 256), 8 waves. Gates GEMM is
// split into two 2-gate passes (i,f then g,o) to cap accumulator pressure.
// xp written in [b][t][j] layout (contiguous per row for k_dec's LDS preload).
// ---------------------------------------------------------------------------
__global__ __launch_bounds__(512) void k_enc(const void* __restrict__ X,
    const float* __restrict__ wmul, const u16* __restrict__ Wenc,
    const u16* __restrict__ Wxp, const void* __restrict__ l2_b,
    const void* __restrict__ da1b, const void* __restrict__ fcw,
    const void* __restrict__ ffw, u16* __restrict__ xp,
    float* __restrict__ cfg, float* __restrict__ cffg,
    const int* __restrict__ flagp){
  __shared__ u16 A_s[32 * 360];        // [m][k]: k<96 = x_tilde2 (pad0), k in [96,352) = h
  __shared__ float w_s[32 * 96];
  __shared__ float cf_s[32], cff_s[32];
  int F = *flagp, sh = 2 - F, ad = F ? 0 : 2;
  int tid = threadIdx.x, wv = tid >> 6, lane = tid & 63, q = lane >> 4, ln = lane & 15;
  int b0 = blockIdx.x * 32;
  for (int i = tid; i < 32 * 96; i += 512){
    int m = i / 96;
    w_s[i] = wmul[(size_t)(b0 + m) * 96 + (i - m * 96)];
  }
  for (int i = tid; i < 32 * 360; i += 512) A_s[i] = 0;
  int u0 = wv * 32 + ln;
  float bi[2], bff[2], bg[2], bo[2], fcr[2], ffr[2], dbr[2];
  #pragma unroll
  for (int ut = 0; ut < 2; ++ut){
    int u = u0 + ut * 16;
    bi[ut]  = ldf(l2_b, u, sh, ad);        bff[ut] = ldf(l2_b, 256 + u, sh, ad);
    bg[ut]  = ldf(l2_b, 512 + u, sh, ad);  bo[ut]  = ldf(l2_b, 768 + u, sh, ad);
    fcr[ut] = ldf(fcw, u, sh, ad);         ffr[ut] = ldf(ffw, 256 + u, sh, ad);
    dbr[ut] = ldf(da1b, u, sh, ad);
  }
  float cst[2][2][4];
  #pragma unroll
  for (int a = 0; a < 2; ++a)
    for (int c = 0; c < 2; ++c)
      for (int r = 0; r < 4; ++r) cst[a][c][r] = 0.f;
  __syncthreads();
  const bf16x8* Wv  = (const bf16x8*)Wenc;
  const bf16x8* Wxv = (const bf16x8*)Wxp;
  const f32x4 vzero = {0.f, 0.f, 0.f, 0.f};
  for (int t = 0; t < 15; ++t){
    // ---- stage x_tilde2 = (a1*a2) .* x_t into A[:, 0:96) ----
    for (int i = tid; i < 32 * 96; i += 512){
      int m = i / 96, dd = i - m * 96;
      float v = 0.f;
      if (dd < 81) v = ldf(X, (size_t)(b0 + m) * 1215 + t * 81 + dd, sh, ad) * w_s[i];
      A_s[m * 360 + dd] = f2bf(v);
    }
    __syncthreads();   // s1
    if (tid < 64){ if (tid < 32) cf_s[tid] = 0.f; else cff_s[tid - 32] = 0.f; }
    // ---- gates GEMM pass A: i,f (K=352) -> iactE, fterm (into cst) ----
    float iactE[2][2][4];
    {
      f32x4 pA[2][2][2];
      #pragma unroll
      for (int mt = 0; mt < 2; ++mt)
        for (int g = 0; g < 2; ++g)
          for (int ut = 0; ut < 2; ++ut) pA[mt][g][ut] = vzero;
      for (int kc = 0; kc < 11; ++kc){
        bf16x8 a0 = *(const bf16x8*)&A_s[ln * 360 + kc * 32 + q * 8];
        bf16x8 a1 = *(const bf16x8*)&A_s[(16 + ln) * 360 + kc * 32 + q * 8];
        #pragma unroll
        for (int g = 0; g < 2; ++g){
          #pragma unroll
          for (int ut = 0; ut < 2; ++ut){
            int ntg = g * 16 + wv * 2 + ut;
            bf16x8 bb = Wv[(ntg * 11 + kc) * 64 + lane];
            pA[0][g][ut] = __builtin_amdgcn_mfma_f32_16x16x32_bf16(a0, bb, pA[0][g][ut], 0, 0, 0);
            pA[1][g][ut] = __builtin_amdgcn_mfma_f32_16x16x32_bf16(a1, bb, pA[1][g][ut], 0, 0, 0);
          }
        }
      }
      #pragma unroll
      for (int mt = 0; mt < 2; ++mt)
        for (int ut = 0; ut < 2; ++ut)
          for (int r = 0; r < 4; ++r){
            float iv = pA[mt][0][ut][r] + bi[ut];
            float fv = pA[mt][1][ut][r] + bff[ut];
            iactE[mt][ut][r] = sigm(iv);
            cst[mt][ut][r] = sigm(fv) * cst[mt][ut][r];
          }
    }
    // ---- gates GEMM pass B: g,o (K=352) ----
    f32x4 pB[2][2][2];
    #pragma unroll
    for (int mt = 0; mt < 2; ++mt)
      for (int g = 0; g < 2; ++g)
        for (int ut = 0; ut < 2; ++ut) pB[mt][g][ut] = vzero;
    for (int kc = 0; kc < 11; ++kc){
      bf16x8 a0 = *(const bf16x8*)&A_s[ln * 360 + kc * 32 + q * 8];
      bf16x8 a1 = *(const bf16x8*)&A_s[(16 + ln) * 360 + kc * 32 + q * 8];
      #pragma unroll
      for (int g = 0; g < 2; ++g){
        #pragma unroll
        for (int ut = 0; ut < 2; ++ut){
          int ntg = (g + 2) * 16 + wv * 2 + ut;
          bf16x8 bb = Wv[(ntg * 11 + kc) * 64 + lane];
          pB[0][g][ut] = __builtin_amdgcn_mfma_f32_16x16x32_bf16(a0, bb, pB[0][g][ut], 0, 0, 0);
          pB[1][g][ut] = __builtin_amdgcn_mfma_f32_16x16x32_bf16(a1, bb, pB[1][g][ut], 0, 0, 0);
        }
      }
    }
    __syncthreads();   // s2
    // ---- LSTM pointwise; h -> A_s[.,96+u]; cf/cff partial reductions ----
    #pragma unroll
    for (int mt = 0; mt < 2; ++mt){
      #pragma unroll
      for (int r = 0; r < 4; ++r){
        int m = mt * 16 + q * 4 + r;
        float pf = 0.f, pff = 0.f;
        #pragma unroll
        for (int ut = 0; ut < 2; ++ut){
          int u = u0 + ut * 16;
          float gv = pB[mt][0][ut][r] + bg[ut];
          float ov = pB[mt][1][ut][r] + bo[ut];
          float c2 = cst[mt][ut][r] + iactE[mt][ut][r] * ftanh(gv);
          float h2 = sigm(ov) * ftanh(c2);
          cst[mt][ut][r] = c2;
          A_s[m * 360 + 96 + u] = f2bf(h2);
          pf  += h2 * fcr[ut];
          pff += h2 * ffr[ut];
        }
        pf  += __shfl_xor(pf, 1);  pf  += __shfl_xor(pf, 2);
        pf  += __shfl_xor(pf, 4);  pf  += __shfl_xor(pf, 8);
        pff += __shfl_xor(pff, 1); pff += __shfl_xor(pff, 2);
        pff += __shfl_xor(pff, 4); pff += __shfl_xor(pff, 8);
        if (ln == 0){ atomicAdd(&cf_s[m], pf); atomicAdd(&cff_s[m], pff); }
      }
    }
    __syncthreads();   // s3
    // ---- xp GEMM: xp_t[m][j] = h_t[m][:] @ W1x^T + da1b, K=256 ----
    f32x4 xpa[2][2];
    #pragma unroll
    for (int mt = 0; mt < 2; ++mt)
      for (int ut = 0; ut < 2; ++ut) xpa[mt][ut] = vzero;
    for (int kc = 0; kc < 8; ++kc){
      bf16x8 a0 = *(const bf16x8*)&A_s[ln * 360 + 96 + kc * 32 + q * 8];
      bf16x8 a1 = *(const bf16x8*)&A_s[(16 + ln) * 360 + 96 + kc * 32 + q * 8];
      #pragma unroll
      for (int ut = 0; ut < 2; ++ut){
        bf16x8 bb = Wxv[((wv * 2 + ut) * 8 + kc) * 64 + lane];
        xpa[0][ut] = __builtin_amdgcn_mfma_f32_16x16x32_bf16(a0, bb, xpa[0][ut], 0, 0, 0);
        xpa[1][ut] = __builtin_amdgcn_mfma_f32_16x16x32_bf16(a1, bb, xpa[1][ut], 0, 0, 0);
      }
    }
    #pragma unroll
    for (int mt = 0; mt < 2; ++mt){
      #pragma unroll
      for (int ut = 0; ut < 2; ++ut){
        int j = u0 + ut * 16;
        #pragma unroll
        for (int r = 0; r < 4; ++r){
          int m = mt * 16 + q * 4 + r;
          xp[((size_t)(b0 + m) * 15 + t) * 256 + j] = f2bf(xpa[mt][ut][r] + dbr[ut]);
        }
      }
    }
    if (tid < 32){
      cfg [(size_t)(b0 + tid) * 15 + t] = cf_s[tid];
      cffg[(size_t)(b0 + tid) * 15 + t] = cff_s[tid];
    }
  }
}

// ---------------------------------------------------------------------------
// k_dec: decoder, 16 rows/block (grid 512), 15 steps, 1 block/CU (LDS ~154 KB).
// xp slice [16 m][15 tt][256 j] LDS-resident (contiguous 120 KB preload;
// tt stride 264 u16, m stride 3960 u16 -> <=2-way bank alias on b128 reads).
// Score phase: proj dumped to LDS (bf16), one thread per (m,tt,jhalf) with a
// SCALAR accumulator over 128 j — no register arrays, no shuffles, no atomics.
// ---------------------------------------------------------------------------
__global__ __launch_bounds__(512) void k_dec(const u16* __restrict__ xpv,
    const float* __restrict__ cfg, const float* __restrict__ cffg,
    const void* __restrict__ y_prev,
    const u16* __restrict__ Wd1, const u16* __restrict__ Wd6,
    const void* __restrict__ da2w, const void* __restrict__ dl_wih,
    const void* __restrict__ dl_b, const void* __restrict__ fcw,
    const void* __restrict__ fcb, const void* __restrict__ ffw,
    const void* __restrict__ ffb, void* __restrict__ outp,
    const int* __restrict__ flagp){
  __shared__ u16 A_s[16 * 552];          // [m][k]: k<256 = d, k in [256,512) = c (bf16)
  __shared__ u16 xp_s[16 * 3960];        // [m][tt][j], tt stride 264
  __shared__ u16 proj_s[16 * 256];       // bf16 proj
  __shared__ u16 w2_s[256];              // bf16 d_a2_w
  __shared__ float psc_s[480];           // raw score partials [m][s][tt]
  __shared__ float beta_s[240], cf_s[240], cff_s[240];
  __shared__ float yt_s[16];
  int F = *flagp, sh = 2 - F, ad = F ? 0 : 2;
  int tid = threadIdx.x, wv = tid >> 6, lane = tid & 63, q = lane >> 4, ln = lane & 15;
  int b0 = blockIdx.x * 16;
  int u0 = wv * 32 + ln;
  float wih_r[4][2], br[4][2];
  #pragma unroll
  for (int ut = 0; ut < 2; ++ut){
    int u = u0 + ut * 16;
    #pragma unroll
    for (int g = 0; g < 4; ++g){
      wih_r[g][ut] = ldf(dl_wih, g * 256 + u, sh, ad);
      br[g][ut]   = ldf(dl_b, g * 256 + u, sh, ad);
    }
  }
  float fcw256 = ldf(fcw, 256, sh, ad), fcbv = ldf(fcb, 0, sh, ad);
  float cst[2][4];
  #pragma unroll
  for (int c = 0; c < 2; ++c)
    for (int r = 0; r < 4; ++r) cst[c][r] = 0.f;
  for (int i = tid; i < 16 * 552; i += 512) A_s[i] = 0;
  if (tid < 240){
    int row = tid / 15, tt = tid - row * 15;
    cf_s [tid] = cfg [(size_t)(b0 + row) * 15 + tt];
    cff_s[tid] = cffg[(size_t)(b0 + row) * 15 + tt];
  }
  if (tid < 256) w2_s[tid] = ldraw(da2w, tid, sh, ad);
  // ---- xp preload: rows contiguous in global ([b][t][j]); transpose-free copy
  //      into padded LDS layout. 7680 uint4 total = 512 thr x 15.
  {
    const uint4* gp = (const uint4*)xpv;
    uint4* xd = (uint4*)xp_s;
    #pragma unroll
    for (int rep = 0; rep < 15; ++rep){
      int i4 = tid + rep * 512;
      int m = i4 / 480, rem = i4 - m * 480;
      int tt = rem >> 5, j8 = rem & 31;
      xd[m * 495 + tt * 33 + j8] = gp[(size_t)(b0 + m) * 480 + rem];
    }
  }
  __syncthreads();
  const bf16x8* W1v = (const bf16x8*)Wd1;
  const bf16x8* W6v = (const bf16x8*)Wd6;
  const f32x4 vzero = {0.f, 0.f, 0.f, 0.f};
  // score-phase thread mapping
  int sm = tid / 30, srem = tid - sm * 30;
  int ss = srem / 15, stt = srem - ss * 15;
  for (int t = 0; t < 15; ++t){
    // ---- GEMM-1: proj[m][j] over K=512 ([d|c]), M=16; dump to proj_s ----
    f32x4 p1[2];
    #pragma unroll
    for (int ut = 0; ut < 2; ++ut) p1[ut] = vzero;
    for (int kc = 0; kc < 16; ++kc){
      bf16x8 a0 = *(const bf16x8*)&A_s[ln * 552 + kc * 32 + q * 8];
      #pragma unroll
      for (int ut = 0; ut < 2; ++ut){
        bf16x8 bb = W1v[((wv * 2 + ut) * 16 + kc) * 64 + lane];
        p1[ut] = __builtin_amdgcn_mfma_f32_16x16x32_bf16(a0, bb, p1[ut], 0, 0, 0);
      }
    }
    #pragma unroll
    for (int ut = 0; ut < 2; ++ut)
      for (int r = 0; r < 4; ++r)
        proj_s[(q * 4 + r) * 256 + u0 + ut * 16] = f2bf(p1[ut][r]);
    __syncthreads();   // P: proj visible
    // ---- score: thread (sm, stt, ss) sums 128 j with a scalar accumulator ----
    if (tid < 480){
      const u16* xr = &xp_s[sm * 3960 + stt * 264 + ss * 128];
      const u16* pr = &proj_s[sm * 256 + ss * 128];
      const u16* wr = &w2_s[ss * 128];
      float acc = 0.f;
      #pragma unroll
      for (int jj = 0; jj < 16; ++jj){
        bf16x8 xv = *(const bf16x8*)&xr[jj * 8];
        bf16x8 pv = *(const bf16x8*)&pr[jj * 8];
        bf16x8 wvv = *(const bf16x8*)&wr[jj * 8];
        #pragma unroll
        for (int e = 0; e < 8; ++e)
          acc += bf2f((u16)wvv[e]) * ftanh(bf2f((u16)pv[e]) + bf2f((u16)xv[e]));
      }
      psc_s[tid] = acc;
    }
    __syncthreads();   // B: partials visible
    // ---- softmax over t + y_tilde (uses cf) ----
    if (tid < 16){
      float s[15]; float mx = -1e30f;
      #pragma unroll
      for (int tt = 0; tt < 15; ++tt){
        s[tt] = psc_s[tid * 30 + tt] + psc_s[tid * 30 + 15 + tt];
        mx = fmaxf(mx, s[tt]);
      }
      float sum = 0.f;
      #pragma unroll
      for (int tt = 0; tt < 15; ++tt){ s[tt] = __expf(s[tt] - mx); sum += s[tt]; }
      float inv = 1.f / sum;
      float yt = fcbv + ldf(y_prev, (size_t)(b0 + tid) * 15 + t, sh, ad) * fcw256;
      #pragma unroll
      for (int tt = 0; tt < 15; ++tt){
        float bv = s[tt] * inv;
        beta_s[tid * 15 + tt] = bv;
        yt += bv * cf_s[tid * 15 + tt];
      }
      yt_s[tid] = yt;
    }
    __syncthreads();   // C: yt/beta visible
    // ---- GEMM-6: gates = d @ dl_whh^T (K=256), M=16, single pass ----
    f32x4 p6[4][2];
    #pragma unroll
    for (int g = 0; g < 4; ++g)
      for (int ut = 0; ut < 2; ++ut) p6[g][ut] = vzero;
    for (int kc = 0; kc < 8; ++kc){
      bf16x8 a0 = *(const bf16x8*)&A_s[ln * 552 + kc * 32 + q * 8];
      #pragma unroll
      for (int g = 0; g < 4; ++g){
        #pragma unroll
        for (int ut = 0; ut < 2; ++ut){
          bf16x8 bb = W6v[((g * 16 + wv * 2 + ut) * 8 + kc) * 64 + lane];
          p6[g][ut] = __builtin_amdgcn_mfma_f32_16x16x32_bf16(a0, bb, p6[g][ut], 0, 0, 0);
        }
      }
    }
    __syncthreads();   // E: A_s reads done before pointwise writes
    // ---- LSTM pointwise: + y_tilde*dl_wih + dl_b ----
    #pragma unroll
    for (int ut = 0; ut < 2; ++ut){
      #pragma unroll
      for (int r = 0; r < 4; ++r){
        int m = q * 4 + r, u = u0 + ut * 16;
        float yt = yt_s[m];
        float iv = p6[0][ut][r] + yt * wih_r[0][ut] + br[0][ut];
        float fv = p6[1][ut][r] + yt * wih_r[1][ut] + br[1][ut];
        float gv = p6[2][ut][r] + yt * wih_r[2][ut] + br[2][ut];
        float ov = p6[3][ut][r] + yt * wih_r[3][ut] + br[3][ut];
        float c2 = sigm(fv) * cst[ut][r] + sigm(iv) * ftanh(gv);
        float d2 = sigm(ov) * ftanh(c2);
        cst[ut][r] = c2;
        A_s[m * 552 + u] = f2bf(d2);
        A_s[m * 552 + 256 + u] = f2bf(c2);
      }
    }
    __syncthreads();   // Fb: A_s stable for next step's GEMMs
  }
  // ---- y_pred = d.ffw[:256] + sum_t beta*cff + ffb ----
  if (tid < 256){
    int m = tid >> 4, l16 = tid & 15;
    float part = 0.f;
    #pragma unroll
    for (int it = 0; it < 16; ++it){
      int h = l16 + it * 16;
      part += bf2f(A_s[m * 552 + h]) * ldf(ffw, h, sh, ad);
    }
    part += __shfl_xor(part, 1); part += __shfl_xor(part, 2);
    part += __shfl_xor(part, 4); part += __shfl_xor(part, 8);
    if (l16 == 0){
      float cx = 0.f;
      #pragma unroll
      for (int tt = 0; tt < 15; ++tt) cx += beta_s[m * 15 + tt] * cff_s[m * 15 + tt];
      float v = part + cx + ldf(ffb, 0, sh, ad);
      if (F) ((u16*)outp)[b0 + m] = f2bf(v);
      else   ((float*)outp)[b0 + m] = v;
    }
  }
}

// ---------------------------------------------------------------------------
extern "C" void kernel_launch(void* const* d_in, const int* in_sizes, int n_in,
                              void* d_out, int out_size, void* d_ws, size_t ws_size,
                              hipStream_t stream){
  (void)in_sizes; (void)n_in; (void)out_size; (void)ws_size;
  const void* X      = d_in[0];
  const void* y_prev = d_in[1];
  const void* e1w    = d_in[2];
  const void* e2w    = d_in[4];
  const void* l2_wih = d_in[9];
  const void* l2_whh = d_in[10];
  const void* l2_b   = d_in[11];
  const void* da1w   = d_in[12];
  const void* da1b   = d_in[13];
  const void* da2w   = d_in[14];
  const void* dl_wih = d_in[16];
  const void* dl_whh = d_in[17];
  const void* dl_b   = d_in[18];
  const void* fc_w   = d_in[19];
  const void* fc_b   = d_in[20];
  const void* ff_w   = d_in[21];
  const void* ff_b   = d_in[22];

  char* ws = (char*)d_ws;
  float* wmul = (float*)(ws + 0);              // 8192*96*4      = 3,145,728
  u16* Wenc   = (u16*)(ws + 3145728);          // 360448*2       =   720,896
  u16* Wd6    = (u16*)(ws + 3866624);          // 262144*2       =   524,288
  u16* Wd1    = (u16*)(ws + 4390912);          // 131072*2       =   262,144
  u16* Wxp    = (u16*)(ws + 4653056);          // 65536*2        =   131,072
  float* cfg  = (float*)(ws + 4784128);        // 8192*15*4      =   491,520
  float* cffg = (float*)(ws + 5275648);        // 8192*15*4      =   491,520
  u16* xp     = (u16*)(ws + 5767168);          // 8192*15*256*2  = 62,914,560
  int* flagp  = (int*)(ws + 68681728);         // 4 B; total ws ~68.7 MB

  k_detect<<<dim3(1),   dim3(64),  0, stream>>>((const u16*)X, flagp);
  k_attn <<<dim3(2048), dim3(256), 0, stream>>>(X, e1w, e2w, wmul, flagp);
  k_pack <<<dim3(3200), dim3(256), 0, stream>>>(l2_wih, l2_whh, dl_whh, da1w,
                                                Wenc, Wd6, Wd1, Wxp, flagp);
  k_enc  <<<dim3(256),  dim3(512), 0, stream>>>(X, wmul, Wenc, Wxp, l2_b, da1b,
                                                fc_w, ff_w, xp, cfg, cffg, flagp);
  k_dec  <<<dim3(512),  dim3(512), 0, stream>>>(xp, cfg, cffg, y_prev, Wd1, Wd6, da2w,
                                                dl_wih, dl_b, fc_w, fc_b, ff_w, ff_b,
                                                d_out, flagp);
}